// Round 8
// baseline (75.087 us; speedup 1.0000x reference)
//
#include <hip/hip_runtime.h>
#include <math.h>

#define BM 60      // modes per batch
#define TT 80      // timesteps
#define NAG 128    // agents
#define NLANES 64
#define NPTS 20
#define NLP (NLANES * NPTS)  // 1280 lane points
#define BIGOFF 1e8f
#define MAGIC 0xC0FFEE00u

// Single launch: blocks [0, B*BM) score one (b,m) each (R7 body: existence
// scan with exact early exit); blocks [B*BM, B*BM+B) select for batch b.
// Fan-in: scoring block publishes (MAGIC<<32)|bits(score) via device-scope
// atomic release store; selection lanes spin on acquire loads. d_ws poison
// (0xAAAAAAAA) != MAGIC so no zeroing dispatch is needed.
__global__ __launch_bounds__(256) void fused_kernel(
    const float* __restrict__ logits,  // (B, M)
    const float* __restrict__ trajs,   // (B, M, T, 3)
    const float* __restrict__ agents,  // (B, NAG, 4)
    const float* __restrict__ amask,   // (B, NAG)
    const float* __restrict__ lanes,   // (B, NLANES, NPTS, 3)
    const float* __restrict__ lmask,   // (B, NLANES)
    unsigned long long* __restrict__ slots,  // (B*M,) flag|score
    float* __restrict__ out,           // traj (B*T*3) then idx (B)
    int B)
{
    __shared__ float s_px[NLP], s_py[NLP];   // lane points SoA (mask in x)
    __shared__ float s_ex[TT], s_ey[TT];
    __shared__ float s_j[2];
    __shared__ float s_cc[4], s_cd[4];
    __shared__ int   s_idx;

    const int tid  = threadIdx.x;  // 0..255
    const int w    = tid >> 6;     // wave 0..3
    const int lane = tid & 63;

    if (blockIdx.x >= (unsigned)(B * BM)) {
        // ================= selection block for batch b =================
        const int b = blockIdx.x - B * BM;
        if (w == 0) {
            float lg = (lane < BM) ? logits[b * BM + lane] : -1e30f;
            float mx = lg;
            for (int off = 32; off > 0; off >>= 1) mx = fmaxf(mx, __shfl_xor(mx, off, 64));
            float e = (lane < BM) ? expf(lg - mx) : 0.0f;
            float sum = e;
            for (int off = 32; off > 0; off >>= 1) sum += __shfl_xor(sum, off, 64);

            float part = -1e30f;
            if (lane < BM) {
                unsigned long long v;
                do {
                    v = __hip_atomic_load(&slots[b * BM + lane],
                                          __ATOMIC_ACQUIRE, __HIP_MEMORY_SCOPE_AGENT);
                } while ((unsigned)(v >> 32) != MAGIC);
                part = __uint_as_float((unsigned)(v & 0xFFFFFFFFu));
            }
            float sc = (lane < BM) ? (e / sum + part) : -1e30f;
            int idx = lane;
            for (int off = 32; off > 0; off >>= 1) {
                const float os = __shfl_xor(sc, off, 64);
                const int   oi = __shfl_xor(idx, off, 64);
                if (os > sc || (os == sc && oi < idx)) { sc = os; idx = oi; }
            }
            if (lane == 0) {
                s_idx = idx;
                out[B * TT * 3 + b] = (float)idx;
            }
        }
        __syncthreads();
        const float* src = trajs + ((size_t)b * BM + s_idx) * TT * 3;
        if (tid < TT * 3) out[b * TT * 3 + tid] = src[tid];
        return;
    }

    // ================= scoring block (R7 body) =================
    const int bm = blockIdx.x;     // b*M + m
    const int b  = bm / BM;

    const float* tr = trajs + (size_t)bm * TT * 3;
    for (int i = tid; i < TT; i += 256) {
        s_ex[i] = tr[3 * i];
        s_ey[i] = tr[3 * i + 1];
    }
    const float* lbase = lanes + (size_t)b * NLP * 3;
    for (int p = tid; p < NLP; p += 256) {
        const float off = (1.0f - lmask[b * NLANES + p / NPTS]) * BIGOFF;
        s_px[p] = lbase[3 * p] + off;
        s_py[p] = lbase[3 * p + 1];
    }
    float ax0, ay0, ax1, ay1;
    {
        const float4* ga4 = (const float4*)(agents + (size_t)b * NAG * 4);
        const float4 a0 = ga4[lane];
        const float4 a1 = ga4[64 + lane];
        ax0 = a0.x + (1.0f - amask[b * NAG + lane]) * BIGOFF;
        ay0 = a0.y;
        ax1 = a1.x + (1.0f - amask[b * NAG + 64 + lane]) * BIGOFF;
        ay1 = a1.y;
    }
    __syncthreads();

    // comfort: jerk[t] = x[t+3]-3x[t+2]+3x[t+1]-x[t], t in [0,77)
    float jsum = 0.0f;
    if (tid < TT - 3) {
        const float jx = s_ex[tid + 3] - 3.0f * s_ex[tid + 2] + 3.0f * s_ex[tid + 1] - s_ex[tid];
        const float jy = s_ey[tid + 3] - 3.0f * s_ey[tid + 2] + 3.0f * s_ey[tid + 1] - s_ey[tid];
        jsum = sqrtf(jx * jx + jy * jy);
    }
    for (int off = 32; off > 0; off >>= 1) jsum += __shfl_xor(jsum, off, 64);
    if (w < 2 && lane == 0) s_j[w] = jsum;

    int ccoll = 0, cdriv = 0;
    const int t0 = w * (TT / 4);
    for (int t = t0; t < t0 + TT / 4; ++t) {
        const float ex = s_ex[t], ey = s_ey[t];  // broadcast reads

        // collision: exists agent with d^2 < 4 (2 register chunks)
        {
            float dx = ex - ax0, dy = ey - ay0;
            unsigned long long m = __ballot(fmaf(dx, dx, dy * dy) < 4.0f);
            if (m == 0ull) {
                dx = ex - ax1; dy = ey - ay1;
                m = __ballot(fmaf(dx, dx, dy * dy) < 4.0f);
            }
            ccoll += (m != 0ull) ? 1 : 0;
        }
        // drivable violation: NO lane point with d^2 <= 9 (20 LDS chunks)
        {
            unsigned long long m = 0ull;
            for (int k = 0; k < NLP / 64; ++k) {
                const int p = k * 64 + lane;
                const float dx = ex - s_px[p];
                const float dy = ey - s_py[p];
                m = __ballot(fmaf(dx, dx, dy * dy) <= 9.0f);
                if (m != 0ull) break;   // witness found: min <= 3, exact
            }
            cdriv += (m == 0ull) ? 1 : 0;
        }
    }
    if (lane == 0) { s_cc[w] = (float)ccoll; s_cd[w] = (float)cdriv; }
    __syncthreads();

    if (tid == 0) {
        const float coll = s_cc[0] + s_cc[1] + s_cc[2] + s_cc[3];
        const float driv = s_cd[0] + s_cd[1] + s_cd[2] + s_cd[3];
        const float comfort  = -((s_j[0] + s_j[1]) / (float)(TT - 3));
        const float progress = s_ex[TT - 1];
        const float score = 0.1f * comfort + 0.5f * progress
                          - 1.0f * (coll / (float)TT)
                          - 0.3f * (driv / (float)TT);
        const unsigned long long enc =
            ((unsigned long long)MAGIC << 32) | (unsigned long long)__float_as_uint(score);
        __hip_atomic_store(&slots[bm], enc, __ATOMIC_RELEASE, __HIP_MEMORY_SCOPE_AGENT);
    }
}

extern "C" void kernel_launch(void* const* d_in, const int* in_sizes, int n_in,
                              void* d_out, int out_size, void* d_ws, size_t ws_size,
                              hipStream_t stream) {
    const float* logits = (const float*)d_in[0];
    const float* trajs  = (const float*)d_in[1];
    const float* agents = (const float*)d_in[2];
    const float* amask  = (const float*)d_in[3];
    const float* lanes  = (const float*)d_in[4];
    const float* lmask  = (const float*)d_in[5];

    const int B = in_sizes[0] / BM;  // 16
    unsigned long long* slots = (unsigned long long*)d_ws;  // B*M slots
    float* out = (float*)d_out;

    fused_kernel<<<B * BM + B, 256, 0, stream>>>(logits, trajs, agents, amask,
                                                 lanes, lmask, slots, out, B);
}

// Round 9
// 70.704 us; speedup vs baseline: 1.0620x; 1.0620x over previous
//
#include <hip/hip_runtime.h>
#include <math.h>

#define BM 60      // modes per batch
#define TT 80      // timesteps
#define NAG 128    // agents
#define NLANES 64
#define NPTS 20
#define NLP (NLANES * NPTS)  // 1280 lane points
#define BIGOFF 1e8f

// One block of 4 waves per (b,m); wave w owns t in [20w, 20w+20).
// Both rule checks are EXISTENCE queries -> chunk-of-64 scan with exact
// early exit on the first witness (branch on ballot = wave-uniform).
// Masks folded into x coordinate (+1e8): masked points can never satisfy
// d^2 < 4 nor d^2 <= 9 — identical booleans to the reference's +1e6 penalty.
__global__ __launch_bounds__(256) void score_kernel(
    const float* __restrict__ trajs,   // (B, M, T, 3)
    const float* __restrict__ agents,  // (B, NAG, 4)
    const float* __restrict__ amask,   // (B, NAG)
    const float* __restrict__ lanes,   // (B, NLANES, NPTS, 3)
    const float* __restrict__ lmask,   // (B, NLANES)
    float* __restrict__ scores)        // (B*M,)
{
    __shared__ float s_px[NLP], s_py[NLP];   // lane points SoA (mask in x)
    __shared__ float s_ex[TT], s_ey[TT];
    __shared__ float s_lm[NLANES];
    __shared__ float s_j[2];
    __shared__ float s_cc[4], s_cd[4];

    const int bm   = blockIdx.x;   // b*M + m
    const int b    = bm / BM;
    const int tid  = threadIdx.x;  // 0..255
    const int w    = tid >> 6;     // wave 0..3
    const int lane = tid & 63;

    // ---- staging ----
    if (tid < NLANES) s_lm[tid] = (1.0f - lmask[b * NLANES + tid]) * BIGOFF;

    const float* tr = trajs + (size_t)bm * TT * 3;
    for (int i = tid; i < TT; i += 256) {
        s_ex[i] = tr[3 * i];
        s_ey[i] = tr[3 * i + 1];
    }
    // agents: 16-byte records -> 4 registers, mask folded into x
    float ax0, ay0, ax1, ay1;
    {
        const float4* ga4 = (const float4*)(agents + (size_t)b * NAG * 4);
        const float4 a0 = ga4[lane];
        const float4 a1 = ga4[64 + lane];
        ax0 = a0.x + (1.0f - amask[b * NAG + lane]) * BIGOFF;
        ay0 = a0.y;
        ax1 = a1.x + (1.0f - amask[b * NAG + 64 + lane]) * BIGOFF;
        ay1 = a1.y;
    }
    __syncthreads();  // s_lm ready (needed by the point-staging loop)

    const float* lbase = lanes + (size_t)b * NLP * 3;
    for (int p = tid; p < NLP; p += 256) {
        s_px[p] = lbase[3 * p] + s_lm[p / NPTS];
        s_py[p] = lbase[3 * p + 1];
    }
    __syncthreads();

    // comfort: jerk[t] = x[t+3]-3x[t+2]+3x[t+1]-x[t], t in [0,77)
    float jsum = 0.0f;
    if (tid < TT - 3) {
        const float jx = s_ex[tid + 3] - 3.0f * s_ex[tid + 2] + 3.0f * s_ex[tid + 1] - s_ex[tid];
        const float jy = s_ey[tid + 3] - 3.0f * s_ey[tid + 2] + 3.0f * s_ey[tid + 1] - s_ey[tid];
        jsum = sqrtf(jx * jx + jy * jy);
    }
    for (int off = 32; off > 0; off >>= 1) jsum += __shfl_xor(jsum, off, 64);
    if (w < 2 && lane == 0) s_j[w] = jsum;

    // ---- rule checks with exact early exit ----
    int ccoll = 0, cdriv = 0;
    const int t0 = w * (TT / 4);
    for (int t = t0; t < t0 + TT / 4; ++t) {
        const float ex = s_ex[t], ey = s_ey[t];  // broadcast reads

        // collision: exists agent with d^2 < 4 (2 register chunks)
        {
            float dx = ex - ax0, dy = ey - ay0;
            unsigned long long m = __ballot(fmaf(dx, dx, dy * dy) < 4.0f);
            if (m == 0ull) {
                dx = ex - ax1; dy = ey - ay1;
                m = __ballot(fmaf(dx, dx, dy * dy) < 4.0f);
            }
            ccoll += (m != 0ull) ? 1 : 0;
        }
        // drivable violation: NO lane point with d^2 <= 9 (20 LDS chunks)
        {
            unsigned long long m = 0ull;
            for (int k = 0; k < NLP / 64; ++k) {
                const int p = k * 64 + lane;
                const float dx = ex - s_px[p];
                const float dy = ey - s_py[p];
                m = __ballot(fmaf(dx, dx, dy * dy) <= 9.0f);
                if (m != 0ull) break;   // witness found: min <= 3, exact
            }
            cdriv += (m == 0ull) ? 1 : 0;
        }
    }
    if (lane == 0) { s_cc[w] = (float)ccoll; s_cd[w] = (float)cdriv; }
    __syncthreads();

    if (tid == 0) {
        const float coll = s_cc[0] + s_cc[1] + s_cc[2] + s_cc[3];
        const float driv = s_cd[0] + s_cd[1] + s_cd[2] + s_cd[3];
        const float comfort  = -((s_j[0] + s_j[1]) / (float)(TT - 3));
        const float progress = s_ex[TT - 1];
        scores[bm] = 0.1f * comfort + 0.5f * progress
                   - 1.0f * (coll / (float)TT)
                   - 0.3f * (driv / (float)TT);
    }
}

// Per-b softmax over M=60 logits, add partial scores, argmax (first-index
// tie-break like jnp.argmax), emit winning trajectory + index.
__global__ __launch_bounds__(64) void select_kernel(
    const float* __restrict__ logits,  // (B, M)
    const float* __restrict__ trajs,   // (B, M, T, 3)
    const float* __restrict__ scores,  // (B*M,)
    float* __restrict__ out,           // traj (B*T*3) then idx (B)
    int B)
{
    const int b    = blockIdx.x;
    const int lane = threadIdx.x;

    float lg = (lane < BM) ? logits[b * BM + lane] : -1e30f;
    float mx = lg;
    for (int off = 32; off > 0; off >>= 1) mx = fmaxf(mx, __shfl_xor(mx, off, 64));
    float e = (lane < BM) ? expf(lg - mx) : 0.0f;
    float sum = e;
    for (int off = 32; off > 0; off >>= 1) sum += __shfl_xor(sum, off, 64);

    float sc = (lane < BM) ? (e / sum + scores[b * BM + lane]) : -1e30f;
    int idx = lane;
    for (int off = 32; off > 0; off >>= 1) {
        float os = __shfl_xor(sc, off, 64);
        int   oi = __shfl_xor(idx, off, 64);
        if (os > sc || (os == sc && oi < idx)) { sc = os; idx = oi; }
    }
    // trajectory copy: 240 floats = 60 float4s, lanes 0..59
    const float4* src4 = (const float4*)(trajs + ((size_t)b * BM + idx) * TT * 3);
    float4* dst4 = (float4*)(out + (size_t)b * TT * 3);
    if (lane < (TT * 3) / 4) dst4[lane] = src4[lane];
    if (lane == 0) out[B * TT * 3 + b] = (float)idx;
}

extern "C" void kernel_launch(void* const* d_in, const int* in_sizes, int n_in,
                              void* d_out, int out_size, void* d_ws, size_t ws_size,
                              hipStream_t stream) {
    const float* logits = (const float*)d_in[0];
    const float* trajs  = (const float*)d_in[1];
    const float* agents = (const float*)d_in[2];
    const float* amask  = (const float*)d_in[3];
    const float* lanes  = (const float*)d_in[4];
    const float* lmask  = (const float*)d_in[5];

    const int B = in_sizes[0] / BM;  // 16
    float* scores = (float*)d_ws;    // B*M floats of scratch
    float* out    = (float*)d_out;

    score_kernel<<<B * BM, 256, 0, stream>>>(trajs, agents, amask, lanes, lmask, scores);
    select_kernel<<<B, 64, 0, stream>>>(logits, trajs, scores, out, B);
}